// Round 12
// baseline (146.662 us; speedup 1.0000x reference)
//
#include <hip/hip_runtime.h>

// Problem constants
#define B_   16
#define L_   6
#define H_   352
#define W_   704
#define HW_  (H_ * W_)          // 247808
#define NIMG (B_ * L_)          // 96
#define NMASK (NIMG * HW_)      // 23,789,568
#define THRESH 0.01f

// Work decomposition: wave = (img, chunk of CH full-width rows)
#define NQ     176              // W/4 quads per row
#define CH     8                // rows per wave (44 chunks * 8 = 352)
#define NCHUNK 44
#define ITEMS  (NIMG * NCHUNK)  // 4224 waves
#define NBLK   (ITEMS / 4)      // 1056 blocks of 4 waves

// OOB sentinel: sigmoid(-1e30) == 0 exactly -> zero-padded confidence map
#define OOBV  -1.0e30f

typedef float f4 __attribute__((ext_vector_type(4)));

__device__ __forceinline__ f4 sig4max(f4 a, f4 b) {
    f4 c;
    c.x = 1.f / (1.f + __expf(-fmaxf(a.x, b.x)));
    c.y = 1.f / (1.f + __expf(-fmaxf(a.y, b.y)));
    c.z = 1.f / (1.f + __expf(-fmaxf(a.z, b.z)));
    c.w = 1.f / (1.f + __expf(-fmaxf(a.w, b.w)));
    return c;
}

// Nontemporal (no-L3-allocate) streaming loads: the input is read exactly once
// per replay and must not thrash the 256 MB L3 against the 190 MB write stream.
__device__ __forceinline__ void raw_load(const float* __restrict__ xb,
                                         int h, int iq, f4& a, f4& b) {
    if ((unsigned)h < (unsigned)H_ && (unsigned)iq < (unsigned)NQ) {
        const size_t off = (size_t)h * W_ + 4 * iq;
        a = __builtin_nontemporal_load((const f4*)(xb + off));
        b = __builtin_nontemporal_load((const f4*)(xb + HW_ + off));
    } else {
        a = (f4){OOBV, OOBV, OOBV, OOBV};
        b = (f4){OOBV, OOBV, OOBV, OOBV};
    }
}

__global__ __launch_bounds__(256, 4) void comm_fused_v8(
    const float* __restrict__ x,      // (B,L,2,H,W)
    const float* __restrict__ gw,     // (1,1,5,5)
    float* __restrict__ out_mask,     // (B*L,1,H,W)
    float* __restrict__ rate,         // scalar
    float* __restrict__ sm_m1)        // out + NMASK (= smoothed base - 1, 16B-aligned)
{
    const int wave = threadIdx.x >> 6;
    const int lane = threadIdx.x & 63;
    const int item = blockIdx.x * 4 + wave;

    const int img   = item / NCHUNK;
    const int chunk = item % NCHUNK;
    const int hA    = chunk * CH;

    const float* xb = x + (size_t)img * (2 * HW_);
    float* __restrict__ sm = sm_m1 + 1;            // true smoothed base

    // Segment quad indices: wave sweeps 3 column segments per row (full width)
    int  iq[3];
    bool outl[3];
    #pragma unroll
    for (int s = 0; s < 3; ++s) {
        iq[s]   = s * 62 - 1 + lane;
        outl[s] = (lane >= 1) && (lane <= 62) && (iq[s] < NQ);
    }

    // Exact separable weights: g2d[i][j] == u[i] * hv[j]
    float u[5], hv[5];
    {
        const float g12 = gw[12];
        #pragma unroll
        for (int i = 0; i < 5; ++i) u[i] = gw[i * 5 + 2];
        #pragma unroll
        for (int j = 0; j < 5; ++j) hv[j] = gw[10 + j] / g12;
    }

    // Rolling conf window (rows h-2..h+1) + raw pending (row h+2), per segment
    f4 c0[3], c1[3], c2[3], c3[3], pa[3], pb[3];
    #pragma unroll
    for (int s = 0; s < 3; ++s) {
        f4 a, b;
        raw_load(xb, hA - 2, iq[s], a, b); c0[s] = sig4max(a, b);
        raw_load(xb, hA - 1, iq[s], a, b); c1[s] = sig4max(a, b);
        raw_load(xb, hA,     iq[s], a, b); c2[s] = sig4max(a, b);
        raw_load(xb, hA + 1, iq[s], a, b); c3[s] = sig4max(a, b);
        raw_load(xb, hA + 2, iq[s], pa[s], pb[s]);
    }

    const bool ego = (img % L_) == 0;
    float cnt = 0.f;

    for (int r = 0; r < CH; ++r) {
        const int h = hA + r;

        // Issue next pending row (h+3) for all 3 segments back-to-back
        f4 na[3], nb[3];
        if (r + 1 < CH) {
            #pragma unroll
            for (int s = 0; s < 3; ++s)
                raw_load(xb, h + 3, iq[s], na[s], nb[s]);
        }

        #pragma unroll
        for (int s = 0; s < 3; ++s) {
            // Finish conf for row h+2
            const f4 c4 = sig4max(pa[s], pb[s]);

            // Vertical 5-tap (registers)
            f4 v;
            v.x = u[0] * c0[s].x; v.y = u[0] * c0[s].y;
            v.z = u[0] * c0[s].z; v.w = u[0] * c0[s].w;
            v.x = fmaf(u[1], c1[s].x, v.x); v.y = fmaf(u[1], c1[s].y, v.y);
            v.z = fmaf(u[1], c1[s].z, v.z); v.w = fmaf(u[1], c1[s].w, v.w);
            v.x = fmaf(u[2], c2[s].x, v.x); v.y = fmaf(u[2], c2[s].y, v.y);
            v.z = fmaf(u[2], c2[s].z, v.z); v.w = fmaf(u[2], c2[s].w, v.w);
            v.x = fmaf(u[3], c3[s].x, v.x); v.y = fmaf(u[3], c3[s].y, v.y);
            v.z = fmaf(u[3], c3[s].z, v.z); v.w = fmaf(u[3], c3[s].w, v.w);
            v.x = fmaf(u[4], c4.x, v.x); v.y = fmaf(u[4], c4.y, v.y);
            v.z = fmaf(u[4], c4.z, v.z); v.w = fmaf(u[4], c4.w, v.w);

            // Horizontal halo from neighbor lanes
            const float lz = __shfl_up(v.z, 1);
            const float lw = __shfl_up(v.w, 1);
            const float rx = __shfl_down(v.x, 1);
            const float ry = __shfl_down(v.y, 1);

            // Horizontal conv on ALL lanes (lane 0's o3 feeds lane 1's store)
            const float s0[8] = { lz, lw, v.x, v.y, v.z, v.w, rx, ry };
            float o0, o1, o2, o3;
            {
                float a;
                a = hv[0] * s0[0];
                a = fmaf(hv[1], s0[1], a); a = fmaf(hv[2], s0[2], a);
                a = fmaf(hv[3], s0[3], a); a = fmaf(hv[4], s0[4], a);
                o0 = a;
                a = hv[0] * s0[1];
                a = fmaf(hv[1], s0[2], a); a = fmaf(hv[2], s0[3], a);
                a = fmaf(hv[3], s0[4], a); a = fmaf(hv[4], s0[5], a);
                o1 = a;
                a = hv[0] * s0[2];
                a = fmaf(hv[1], s0[3], a); a = fmaf(hv[2], s0[4], a);
                a = fmaf(hv[3], s0[5], a); a = fmaf(hv[4], s0[6], a);
                o2 = a;
                a = hv[0] * s0[3];
                a = fmaf(hv[1], s0[4], a); a = fmaf(hv[2], s0[5], a);
                a = fmaf(hv[3], s0[6], a); a = fmaf(hv[4], s0[7], a);
                o3 = a;
            }
            const float o3l = __shfl_up(o3, 1);   // left neighbor's col 4iq-1

            if (outl[s]) {
                const size_t idx = (size_t)img * HW_ + (size_t)h * W_ + 4 * iq[s];

                // smoothed: shifted, 16B-aligned nontemporal f4 store
                if (iq[s] > 0) {
                    f4 sv = { o3l, o0, o1, o2 };
                    __builtin_nontemporal_store(sv, (f4*)(sm_m1 + idx));
                } else {  // quad 0: cols 0..2 scalar (no col -1 write)
                    __builtin_nontemporal_store(o0, sm + idx + 0);
                    __builtin_nontemporal_store(o1, sm + idx + 1);
                    __builtin_nontemporal_store(o2, sm + idx + 2);
                }
                if (iq[s] == NQ - 1)              // image last col (703)
                    __builtin_nontemporal_store(o3, sm + idx + 3);

                // mask + rate (rate counted PRE-ego force)
                float m0 = (o0 > THRESH) ? 1.f : 0.f;
                float m1 = (o1 > THRESH) ? 1.f : 0.f;
                float m2 = (o2 > THRESH) ? 1.f : 0.f;
                float m3 = (o3 > THRESH) ? 1.f : 0.f;
                cnt += m0 + m1 + m2 + m3;
                f4 mv = ego ? (f4){1.f, 1.f, 1.f, 1.f} : (f4){m0, m1, m2, m3};
                __builtin_nontemporal_store(mv, (f4*)(out_mask + idx));
            }

            // Shift window
            c0[s] = c1[s]; c1[s] = c2[s]; c2[s] = c3[s]; c3[s] = c4;
            if (r + 1 < CH) { pa[s] = na[s]; pb[s] = nb[s]; }
        }
    }

    // Per-wave reduce -> one atomic per wave (no LDS, no barriers)
    #pragma unroll
    for (int off = 32; off >= 1; off >>= 1)
        cnt += __shfl_down(cnt, off);
    if (lane == 0)
        atomicAdd(rate, cnt * (1.f / (float)NMASK));
}

extern "C" void kernel_launch(void* const* d_in, const int* in_sizes, int n_in,
                              void* d_out, int out_size, void* d_ws, size_t ws_size,
                              hipStream_t stream) {
    const float* x  = (const float*)d_in[0];
    const float* gw = (const float*)d_in[1];
    float* out      = (float*)d_out;

    float* mask_out = out;               // 23,789,568
    float* rate_out = out + NMASK;       // 1
    float* sm_m1    = out + NMASK;       // smoothed base - 1 (16B-aligned)

    // rate slot overlaps sm_m1[0], which no smoothed store ever touches
    // (f4 stores start at idx>=4; scalar path writes sm_m1+1+idx, idx>=0).
    hipMemsetAsync(rate_out, 0, sizeof(float), stream);

    dim3 grid(NBLK, 1, 1);               // 1056 blocks x 256 threads = 4224 waves
    dim3 block(256, 1, 1);
    comm_fused_v8<<<grid, block, 0, stream>>>(x, gw, mask_out, rate_out, sm_m1);
}